// Round 3
// baseline (101.879 us; speedup 1.0000x reference)
//
#include <hip/hip_runtime.h>
#include <math.h>

#define NBATCH 8
#define NUM    4096
#define CDIM   1024
#define KP     16        // prototype columns
#define KC     17        // cost columns incl. trash
#define KSTR   20        // padded row stride for K in ws
#define NITER  100
#define FEPS   1e-12f

// ws layout (float offsets)
#define WS_PN  0                          // [8][16][1024] normalized prototypes
#define WS_K   (NBATCH*KP*CDIM)           // [8][4096][20] K matrix
#define WS_NBG (WS_K + NBATCH*NUM*KSTR)   // [8] num_bg per batch
// total ~3.15 MB of ws

// ---------------- kernel A: normalize prototypes + num_bg ----------------
__global__ __launch_bounds__(256) void prep_kernel(
    const float* __restrict__ protos, const int* __restrict__ masks,
    float* __restrict__ pn, float* __restrict__ numbg) {
  int bb = blockIdx.x;
  int t = threadIdx.x;
  int w = t >> 6, lane = t & 63;

  // each wave normalizes protos w, w+4, w+8, w+12 (lane owns 16 c-elems)
  #pragma unroll
  for (int pi = 0; pi < 4; ++pi) {
    int p = w + 4 * pi;
    const float* src = protos + ((size_t)(bb * KP + p)) * CDIM + lane * 16;
    float f[16];
    #pragma unroll
    for (int q = 0; q < 4; ++q) {
      float4 v = *(const float4*)(src + 4 * q);
      f[4*q+0] = v.x; f[4*q+1] = v.y; f[4*q+2] = v.z; f[4*q+3] = v.w;
    }
    float ss = 0.f;
    #pragma unroll
    for (int i = 0; i < 16; ++i) ss += f[i] * f[i];
    #pragma unroll
    for (int m = 1; m < 64; m <<= 1) ss += __shfl_xor(ss, m, 64);
    float rn = 1.0f / fmaxf(sqrtf(ss), FEPS);
    float* dst = pn + ((size_t)(bb * KP + p)) * CDIM + lane * 16;
    #pragma unroll
    for (int q = 0; q < 4; ++q) {
      float4 v = make_float4(f[4*q+0]*rn, f[4*q+1]*rn, f[4*q+2]*rn, f[4*q+3]*rn);
      *(float4*)(dst + 4 * q) = v;
    }
  }

  // num_bg = count(masks == 0) per batch
  int cnt = 0;
  for (int i = t; i < NUM; i += 256) cnt += (masks[bb * NUM + i] == 0);
  float c = (float)cnt;
  #pragma unroll
  for (int m = 1; m < 64; m <<= 1) c += __shfl_xor(c, m, 64);
  __shared__ float red[4];
  if (lane == 0) red[w] = c;
  __syncthreads();
  if (t == 0) numbg[bb] = red[0] + red[1] + red[2] + red[3];
}

// ---------------- kernel B: att + K build ----------------
// grid (32, 8), block 512. Block handles 128 rows of one batch.
// Wave pair: even wave -> protos 0..7 (+trash col), odd wave -> protos 8..15.
// pn/Kmat MUST be distinct __restrict__ args: when both were derived from the
// same ws pointer, stores to Kmat forced re-loads of all 128 pr values every
// row (round-2: VGPR=84, 92 us, 774 GB/s).
__global__ __launch_bounds__(512, 2) void attk_kernel(
    const float* __restrict__ feat, const int* __restrict__ masks,
    const float* __restrict__ pn, float* __restrict__ Kmat) {
  int bb  = blockIdx.y;
  int grp = blockIdx.x;              // 0..31
  int t = threadIdx.x;
  int w = t >> 6, lane = t & 63;
  int ph   = w & 1;                  // proto half
  int rsub = w >> 1;                 // 0..3

  // per-lane slice of 8 normalized prototypes (c = lane*16 .. +15)
  float pr[8][16];
  #pragma unroll
  for (int pp = 0; pp < 8; ++pp) {
    const float* src = pn + ((size_t)(bb * KP + ph * 8 + pp)) * CDIM + lane * 16;
    #pragma unroll
    for (int q = 0; q < 4; ++q) {
      float4 v = *(const float4*)(src + 4 * q);
      pr[pp][4*q+0] = v.x; pr[pp][4*q+1] = v.y; pr[pp][4*q+2] = v.z; pr[pp][4*q+3] = v.w;
    }
  }

  const float* fb = feat + (size_t)bb * NUM * CDIM;
  float* Kb = Kmat + (size_t)bb * NUM * KSTR;

  for (int i = 0; i < 32; ++i) {
    int n = grp * 128 + rsub + 4 * i;
    const float* fr = fb + (size_t)n * CDIM + lane * 16;
    float f[16];
    #pragma unroll
    for (int q = 0; q < 4; ++q) {
      float4 v = *(const float4*)(fr + 4 * q);
      f[4*q+0] = v.x; f[4*q+1] = v.y; f[4*q+2] = v.z; f[4*q+3] = v.w;
    }
    float ss = 0.f;
    #pragma unroll
    for (int c = 0; c < 16; ++c) ss += f[c] * f[c];
    float d[8];
    #pragma unroll
    for (int pp = 0; pp < 8; ++pp) {
      float acc = 0.f;
      #pragma unroll
      for (int c = 0; c < 16; ++c) acc += f[c] * pr[pp][c];
      d[pp] = acc;
    }
    // butterfly reduce ss + d[0..7] across 64 lanes
    #pragma unroll
    for (int m = 1; m < 64; m <<= 1) {
      ss += __shfl_xor(ss, m, 64);
      #pragma unroll
      for (int pp = 0; pp < 8; ++pp) d[pp] += __shfl_xor(d[pp], m, 64);
    }
    if (lane == 0) {
      float rn = 1.0f / fmaxf(sqrtf(ss), FEPS);
      float kv[8];
      #pragma unroll
      for (int pp = 0; pp < 8; ++pp)
        kv[pp] = expf((d[pp] * rn - 1.0f) * 20.0f);   // exp(-(1-att)/0.05)
      float* dst = Kb + (size_t)n * KSTR + ph * 8;
      *(float4*)(dst + 0) = make_float4(kv[0], kv[1], kv[2], kv[3]);
      *(float4*)(dst + 4) = make_float4(kv[4], kv[5], kv[6], kv[7]);
      if (ph == 0) {
        int mv = masks[bb * NUM + n];
        // exp(-2/0.05) = exp(-40), or exp(0)=1
        Kb[(size_t)n * KSTR + 16] = (mv > 0) ? 4.248354255291589e-18f : 1.0f;
      }
    }
  }
}

// ---------------- kernel C: 100 Sinkhorn iterations + epilogue ----------------
// 8 blocks (one per batch) x 512 threads; thread owns rows t + 512*j, j=0..7;
// K rows live in registers for the whole loop.
// launch_bounds(512,2): 256-VGPR budget so kreg[8][17] stays in registers
// (round-0 compiled at 88 VGPRs -> whole array spilled to scratch).
__global__ __launch_bounds__(512, 2) void sinkhorn_kernel(
    const float* __restrict__ Kmat, const float* __restrict__ numbg,
    float* __restrict__ out) {
  int bb = blockIdx.x;
  int t = threadIdx.x;
  const float* Kb = Kmat + (size_t)bb * NUM * KSTR;

  float kreg[8][KC];
  #pragma unroll
  for (int j = 0; j < 8; ++j) {
    int n = t + 512 * j;
    const float* kr = Kb + (size_t)n * KSTR;
    #pragma unroll
    for (int q = 0; q < 4; ++q) {
      float4 v = *(const float4*)(kr + 4 * q);
      kreg[j][4*q+0] = v.x; kreg[j][4*q+1] = v.y; kreg[j][4*q+2] = v.z; kreg[j][4*q+3] = v.w;
    }
    kreg[j][16] = kr[16];
  }

  float nbg   = numbg[bb];
  float rowp  = (4096.0f - nbg) * (1.0f / (16.0f * 4096.0f)); // row[k<16]
  float row16 = nbg * (1.0f / 4096.0f);                        // row[16]
  const float col = 1.0f / 4096.0f;

  __shared__ float vlds[KC];
  __shared__ float part[KC][520];
  __shared__ int   flags[2];          // parity-buffered "not converged" flags
  if (t < KC) vlds[t] = 1.0f;
  if (t == 0) { flags[0] = 0; flags[1] = 0; }
  __syncthreads();

  float u[8];
  #pragma unroll 1
  for (int it = 0; it < NITER; ++it) {
    float vr[KC];
    #pragma unroll
    for (int p = 0; p < KC; ++p) vr[p] = vlds[p];
    float s[KC];
    #pragma unroll
    for (int p = 0; p < KC; ++p) s[p] = 0.f;
    #pragma unroll
    for (int j = 0; j < 8; ++j) {
      float dot = 0.f;
      #pragma unroll
      for (int p = 0; p < KC; ++p) dot += kreg[j][p] * vr[p];
      float uu = col * __builtin_amdgcn_rcpf(fmaxf(dot, FEPS));
      u[j] = uu;
      #pragma unroll
      for (int p = 0; p < KC; ++p) s[p] += kreg[j][p] * uu;
    }
    #pragma unroll
    for (int p = 0; p < KC; ++p) part[p][t] = s[p];
    // reset this iteration's flag before barrier1; the only earlier readers
    // of slot (it&1) finished two barriers ago (iter it-2's check).
    if (t == 0) flags[it & 1] = 0;
    __syncthreads();
    // stage 2: 17 groups x 16 threads sum 512 partials each
    if (t < 272) {
      int k = t >> 4, i = t & 15;
      float acc = 0.f;
      #pragma unroll
      for (int j = 0; j < 32; ++j) acc += part[k][i + 16 * j];
      acc += __shfl_xor(acc, 1, 64);
      acc += __shfl_xor(acc, 2, 64);
      acc += __shfl_xor(acc, 4, 64);
      acc += __shfl_xor(acc, 8, 64);
      if (i == 0) {
        float rw = (k < KP) ? rowp : row16;
        float vold = vlds[k];
        float vnew = rw * __builtin_amdgcn_rcpf(fmaxf(acc, FEPS));
        vlds[k] = vnew;
        // benign same-value race: any non-converged k sets the flag to 1
        if (fabsf(vnew - vold) > 1e-6f * fabsf(vnew)) flags[it & 1] = 1;
      }
    }
    __syncthreads();
    if (flags[it & 1] == 0) break;   // converged: remaining ref iters are no-ops
  }

  // epilogue: T = u * K * v * 4096, relu, drop trash col
  float vr[KC];
  #pragma unroll
  for (int p = 0; p < KC; ++p) vr[p] = vlds[p];
  float* ob = out + (size_t)bb * NUM * KP;
  #pragma unroll
  for (int j = 0; j < 8; ++j) {
    int n = t + 512 * j;
    float uu = u[j] * 4096.0f;
    float* dst = ob + (size_t)n * KP;
    #pragma unroll
    for (int q = 0; q < 4; ++q) {
      float4 v;
      v.x = fmaxf(uu * kreg[j][4*q+0] * vr[4*q+0], 0.f);
      v.y = fmaxf(uu * kreg[j][4*q+1] * vr[4*q+1], 0.f);
      v.z = fmaxf(uu * kreg[j][4*q+2] * vr[4*q+2], 0.f);
      v.w = fmaxf(uu * kreg[j][4*q+3] * vr[4*q+3], 0.f);
      *(float4*)(dst + 4 * q) = v;
    }
  }
}

extern "C" void kernel_launch(void* const* d_in, const int* in_sizes, int n_in,
                              void* d_out, int out_size, void* d_ws, size_t ws_size,
                              hipStream_t stream) {
  const float* feat   = (const float*)d_in[0];
  const float* protos = (const float*)d_in[1];
  const int*   masks  = (const int*)d_in[2];
  float* out = (float*)d_out;
  float* ws  = (float*)d_ws;

  float* pn    = ws + WS_PN;
  float* Kmat  = ws + WS_K;
  float* numbg = ws + WS_NBG;

  hipLaunchKernelGGL(prep_kernel, dim3(NBATCH), dim3(256), 0, stream,
                     protos, masks, pn, numbg);
  hipLaunchKernelGGL(attk_kernel, dim3(32, NBATCH), dim3(512), 0, stream,
                     feat, masks, pn, Kmat);
  hipLaunchKernelGGL(sinkhorn_kernel, dim3(NBATCH), dim3(512), 0, stream,
                     Kmat, numbg, out);
}

// Round 4
// 89.374 us; speedup vs baseline: 1.1399x; 1.1399x over previous
//
#include <hip/hip_runtime.h>
#include <math.h>

#define NBATCH 8
#define NUM    4096
#define CDIM   1024
#define KP     16        // prototype columns
#define KC     17        // cost columns incl. trash
#define KSTR   20        // padded row stride for K in ws
#define NITER  100
#define FEPS   1e-12f

// ws layout (float offsets)
#define WS_PN  0                          // [8][16][1024] normalized prototypes
#define WS_K   (NBATCH*KP*CDIM)           // [8][4096][20] K matrix
#define WS_NBG (WS_K + NBATCH*NUM*KSTR)   // [8] num_bg per batch
// total ~3.15 MB of ws

// ---------------- kernel A: normalize prototypes + num_bg ----------------
__global__ __launch_bounds__(256) void prep_kernel(
    const float* __restrict__ protos, const int* __restrict__ masks,
    float* __restrict__ pn, float* __restrict__ numbg) {
  int bb = blockIdx.x;
  int t = threadIdx.x;
  int w = t >> 6, lane = t & 63;

  // each wave normalizes protos w, w+4, w+8, w+12 (lane owns 16 c-elems)
  #pragma unroll
  for (int pi = 0; pi < 4; ++pi) {
    int p = w + 4 * pi;
    const float* src = protos + ((size_t)(bb * KP + p)) * CDIM + lane * 16;
    float f[16];
    #pragma unroll
    for (int q = 0; q < 4; ++q) {
      float4 v = *(const float4*)(src + 4 * q);
      f[4*q+0] = v.x; f[4*q+1] = v.y; f[4*q+2] = v.z; f[4*q+3] = v.w;
    }
    float ss = 0.f;
    #pragma unroll
    for (int i = 0; i < 16; ++i) ss += f[i] * f[i];
    #pragma unroll
    for (int m = 1; m < 64; m <<= 1) ss += __shfl_xor(ss, m, 64);
    float rn = 1.0f / fmaxf(sqrtf(ss), FEPS);
    float* dst = pn + ((size_t)(bb * KP + p)) * CDIM + lane * 16;
    #pragma unroll
    for (int q = 0; q < 4; ++q) {
      float4 v = make_float4(f[4*q+0]*rn, f[4*q+1]*rn, f[4*q+2]*rn, f[4*q+3]*rn);
      *(float4*)(dst + 4 * q) = v;
    }
  }

  // num_bg = count(masks == 0) per batch
  int cnt = 0;
  for (int i = t; i < NUM; i += 256) cnt += (masks[bb * NUM + i] == 0);
  float c = (float)cnt;
  #pragma unroll
  for (int m = 1; m < 64; m <<= 1) c += __shfl_xor(c, m, 64);
  __shared__ float red[4];
  if (lane == 0) red[w] = c;
  __syncthreads();
  if (t == 0) numbg[bb] = red[0] + red[1] + red[2] + red[3];
}

// ---------------- kernel B: att + K build ----------------
// grid (32, 8), block 512. Block handles 128 rows of one batch.
// Wave pair: even wave -> protos 0..7 (+trash col), odd wave -> protos 8..15.
// The asm pin below is load-bearing: without it the allocator rematerializes
// the pr loads inside the row loop (rounds 2-3: VGPR=84, ~100 us, 3x VMEM).
__global__ __launch_bounds__(512, 2) void attk_kernel(
    const float* __restrict__ feat, const int* __restrict__ masks,
    const float* __restrict__ pn, float* __restrict__ Kmat) {
  int bb  = blockIdx.y;
  int grp = blockIdx.x;              // 0..31
  int t = threadIdx.x;
  int w = t >> 6, lane = t & 63;
  int ph   = w & 1;                  // proto half
  int rsub = w >> 1;                 // 0..3

  // per-lane slice of 8 normalized prototypes (c = lane*16 .. +15)
  float pr[8][16];
  #pragma unroll
  for (int pp = 0; pp < 8; ++pp) {
    const float* src = pn + ((size_t)(bb * KP + ph * 8 + pp)) * CDIM + lane * 16;
    #pragma unroll
    for (int q = 0; q < 4; ++q) {
      float4 v = *(const float4*)(src + 4 * q);
      pr[pp][4*q+0] = v.x; pr[pp][4*q+1] = v.y; pr[pp][4*q+2] = v.z; pr[pp][4*q+3] = v.w;
    }
  }
  // Pin: values now originate from an opaque asm, so they cannot be
  // rematerialized by re-loading from pn inside the loop; they must stay
  // resident in VGPRs (128 regs, budget 256 at waves-per-eu=2).
  #pragma unroll
  for (int pp = 0; pp < 8; ++pp)
    #pragma unroll
    for (int c = 0; c < 16; ++c)
      asm volatile("" : "+v"(pr[pp][c]));

  const float* fb = feat + (size_t)bb * NUM * CDIM;
  float* Kb = Kmat + (size_t)bb * NUM * KSTR;

  for (int i = 0; i < 32; ++i) {
    int n = grp * 128 + rsub + 4 * i;
    const float* fr = fb + (size_t)n * CDIM + lane * 16;
    float f[16];
    #pragma unroll
    for (int q = 0; q < 4; ++q) {
      float4 v = *(const float4*)(fr + 4 * q);
      f[4*q+0] = v.x; f[4*q+1] = v.y; f[4*q+2] = v.z; f[4*q+3] = v.w;
    }
    float ss = 0.f;
    #pragma unroll
    for (int c = 0; c < 16; ++c) ss += f[c] * f[c];
    float d[8];
    #pragma unroll
    for (int pp = 0; pp < 8; ++pp) {
      float acc = 0.f;
      #pragma unroll
      for (int c = 0; c < 16; ++c) acc += f[c] * pr[pp][c];
      d[pp] = acc;
    }
    // butterfly reduce ss + d[0..7] across 64 lanes
    #pragma unroll
    for (int m = 1; m < 64; m <<= 1) {
      ss += __shfl_xor(ss, m, 64);
      #pragma unroll
      for (int pp = 0; pp < 8; ++pp) d[pp] += __shfl_xor(d[pp], m, 64);
    }
    if (lane == 0) {
      float rn = 1.0f / fmaxf(sqrtf(ss), FEPS);
      float kv[8];
      #pragma unroll
      for (int pp = 0; pp < 8; ++pp)
        kv[pp] = __expf((d[pp] * rn - 1.0f) * 20.0f);   // exp(-(1-att)/0.05)
      float* dst = Kb + (size_t)n * KSTR + ph * 8;
      *(float4*)(dst + 0) = make_float4(kv[0], kv[1], kv[2], kv[3]);
      *(float4*)(dst + 4) = make_float4(kv[4], kv[5], kv[6], kv[7]);
      if (ph == 0) {
        int mv = masks[bb * NUM + n];
        // exp(-2/0.05) = exp(-40), or exp(0)=1
        Kb[(size_t)n * KSTR + 16] = (mv > 0) ? 4.248354255291589e-18f : 1.0f;
      }
    }
  }
}

// ---------------- kernel C: 100 Sinkhorn iterations + epilogue ----------------
// 8 blocks (one per batch) x 512 threads; thread owns rows t + 512*j, j=0..7;
// K rows live in registers for the whole loop.
// launch_bounds(512,2): 256-VGPR budget so kreg[8][17] stays in registers
// (round-0 compiled at 88 VGPRs -> whole array spilled to scratch).
__global__ __launch_bounds__(512, 2) void sinkhorn_kernel(
    const float* __restrict__ Kmat, const float* __restrict__ numbg,
    float* __restrict__ out) {
  int bb = blockIdx.x;
  int t = threadIdx.x;
  const float* Kb = Kmat + (size_t)bb * NUM * KSTR;

  float kreg[8][KC];
  #pragma unroll
  for (int j = 0; j < 8; ++j) {
    int n = t + 512 * j;
    const float* kr = Kb + (size_t)n * KSTR;
    #pragma unroll
    for (int q = 0; q < 4; ++q) {
      float4 v = *(const float4*)(kr + 4 * q);
      kreg[j][4*q+0] = v.x; kreg[j][4*q+1] = v.y; kreg[j][4*q+2] = v.z; kreg[j][4*q+3] = v.w;
    }
    kreg[j][16] = kr[16];
  }

  float nbg   = numbg[bb];
  float rowp  = (4096.0f - nbg) * (1.0f / (16.0f * 4096.0f)); // row[k<16]
  float row16 = nbg * (1.0f / 4096.0f);                        // row[16]
  const float col = 1.0f / 4096.0f;

  __shared__ float vlds[KC];
  __shared__ float part[KC][520];
  __shared__ int   flags[2];          // parity-buffered "not converged" flags
  if (t < KC) vlds[t] = 1.0f;
  if (t == 0) { flags[0] = 0; flags[1] = 0; }
  __syncthreads();

  float u[8];
  #pragma unroll 1
  for (int it = 0; it < NITER; ++it) {
    float vr[KC];
    #pragma unroll
    for (int p = 0; p < KC; ++p) vr[p] = vlds[p];
    float s[KC];
    #pragma unroll
    for (int p = 0; p < KC; ++p) s[p] = 0.f;
    #pragma unroll
    for (int j = 0; j < 8; ++j) {
      float dot = 0.f;
      #pragma unroll
      for (int p = 0; p < KC; ++p) dot += kreg[j][p] * vr[p];
      float uu = col * __builtin_amdgcn_rcpf(fmaxf(dot, FEPS));
      u[j] = uu;
      #pragma unroll
      for (int p = 0; p < KC; ++p) s[p] += kreg[j][p] * uu;
    }
    #pragma unroll
    for (int p = 0; p < KC; ++p) part[p][t] = s[p];
    // reset this iteration's flag before barrier1; the only earlier readers
    // of slot (it&1) finished two barriers ago (iter it-2's check).
    if (t == 0) flags[it & 1] = 0;
    __syncthreads();
    // stage 2: 17 groups x 16 threads sum 512 partials each
    if (t < 272) {
      int k = t >> 4, i = t & 15;
      float acc = 0.f;
      #pragma unroll
      for (int j = 0; j < 32; ++j) acc += part[k][i + 16 * j];
      acc += __shfl_xor(acc, 1, 64);
      acc += __shfl_xor(acc, 2, 64);
      acc += __shfl_xor(acc, 4, 64);
      acc += __shfl_xor(acc, 8, 64);
      if (i == 0) {
        float rw = (k < KP) ? rowp : row16;
        float vold = vlds[k];
        float vnew = rw * __builtin_amdgcn_rcpf(fmaxf(acc, FEPS));
        vlds[k] = vnew;
        // benign same-value race: any non-converged k sets the flag to 1
        if (fabsf(vnew - vold) > 1e-6f * fabsf(vnew)) flags[it & 1] = 1;
      }
    }
    __syncthreads();
    if (flags[it & 1] == 0) break;   // converged: remaining ref iters are no-ops
  }

  // epilogue: T = u * K * v * 4096, relu, drop trash col
  float vr[KC];
  #pragma unroll
  for (int p = 0; p < KC; ++p) vr[p] = vlds[p];
  float* ob = out + (size_t)bb * NUM * KP;
  #pragma unroll
  for (int j = 0; j < 8; ++j) {
    int n = t + 512 * j;
    float uu = u[j] * 4096.0f;
    float* dst = ob + (size_t)n * KP;
    #pragma unroll
    for (int q = 0; q < 4; ++q) {
      float4 v;
      v.x = fmaxf(uu * kreg[j][4*q+0] * vr[4*q+0], 0.f);
      v.y = fmaxf(uu * kreg[j][4*q+1] * vr[4*q+1], 0.f);
      v.z = fmaxf(uu * kreg[j][4*q+2] * vr[4*q+2], 0.f);
      v.w = fmaxf(uu * kreg[j][4*q+3] * vr[4*q+3], 0.f);
      *(float4*)(dst + 4 * q) = v;
    }
  }
}

extern "C" void kernel_launch(void* const* d_in, const int* in_sizes, int n_in,
                              void* d_out, int out_size, void* d_ws, size_t ws_size,
                              hipStream_t stream) {
  const float* feat   = (const float*)d_in[0];
  const float* protos = (const float*)d_in[1];
  const int*   masks  = (const int*)d_in[2];
  float* out = (float*)d_out;
  float* ws  = (float*)d_ws;

  float* pn    = ws + WS_PN;
  float* Kmat  = ws + WS_K;
  float* numbg = ws + WS_NBG;

  hipLaunchKernelGGL(prep_kernel, dim3(NBATCH), dim3(256), 0, stream,
                     protos, masks, pn, numbg);
  hipLaunchKernelGGL(attk_kernel, dim3(32, NBATCH), dim3(512), 0, stream,
                     feat, masks, pn, Kmat);
  hipLaunchKernelGGL(sinkhorn_kernel, dim3(NBATCH), dim3(512), 0, stream,
                     Kmat, numbg, out);
}

// Round 5
// 56.216 us; speedup vs baseline: 1.8123x; 1.5898x over previous
//
#include <hip/hip_runtime.h>
#include <hip/hip_bf16.h>
#include <math.h>

#define NBATCH 8
#define NUM    4096
#define CDIM   1024
#define KP     16        // prototype columns
#define KC     17        // cost columns incl. trash
#define KSTR   20        // padded row stride for K in ws
#define NITER  100
#define NSTEP  32        // K-steps of 32 c each (32*32 = 1024)
#define FEPS   1e-12f

typedef __attribute__((ext_vector_type(8))) short v8s;    // 8 bf16 (4 VGPR)
typedef __attribute__((ext_vector_type(4))) float v4f;    // MFMA acc

// ws layout (float offsets) — total 786440 floats ~= 3.15 MB (same as prior rounds)
#define WS_BHI 0                            // [8][32][64] v8s  (65536 float-slots)
#define WS_BLO 65536                        // [8][32][64] v8s
#define WS_K   131072                       // [8][4096][20] f32 K matrix
#define WS_NBG (WS_K + NBATCH*NUM*KSTR)     // [8] num_bg

// fp32 -> bf16 hi/lo split (hi + lo reconstructs v to ~2^-17 rel)
__device__ inline void f2hl(float v, unsigned short& h, unsigned short& l) {
  __hip_bfloat16 bh = __float2bfloat16(v);
  h = __builtin_bit_cast(unsigned short, bh);
  float hf = __uint_as_float(((unsigned int)h) << 16);
  __hip_bfloat16 bl = __float2bfloat16(v - hf);
  l = __builtin_bit_cast(unsigned short, bl);
}

// ---------------- kernel A: proto norms + num_bg + B-fragment build ----------------
// grid (8), block 256. Packs normalized prototypes into MFMA B-frag order
// (hi/lo bf16) so attk can load B with one b128 per matrix per k-step.
// k-map (must match attk's A loads): k(l,j) = (l>>4)*4 + (j&3) + 16*(j>>2).
__global__ __launch_bounds__(256) void prep_kernel(
    const float* __restrict__ protos, const int* __restrict__ masks,
    float* __restrict__ ws) {
  int bb = blockIdx.x;
  int t = threadIdx.x;
  int w = t >> 6, lane = t & 63;

  __shared__ float rnl[KP];
  __shared__ float red[4];

  // phase 1: per-proto 1/||p||  (wave w handles protos w, w+4, w+8, w+12)
  #pragma unroll
  for (int pi = 0; pi < 4; ++pi) {
    int p = w + 4 * pi;
    const float* src = protos + ((size_t)(bb * KP + p)) * CDIM + lane * 16;
    float ss = 0.f;
    #pragma unroll
    for (int q = 0; q < 4; ++q) {
      float4 v = *(const float4*)(src + 4 * q);
      ss += v.x * v.x + v.y * v.y + v.z * v.z + v.w * v.w;
    }
    #pragma unroll
    for (int m = 1; m < 64; m <<= 1) ss += __shfl_xor(ss, m, 64);
    if (lane == 0) rnl[p] = 1.0f / fmaxf(sqrtf(ss), FEPS);
  }

  // num_bg = count(masks == 0)
  int cnt = 0;
  for (int i = t; i < NUM; i += 256) cnt += (masks[bb * NUM + i] == 0);
  float c = (float)cnt;
  #pragma unroll
  for (int m = 1; m < 64; m <<= 1) c += __shfl_xor(c, m, 64);
  if (lane == 0) red[w] = c;
  __syncthreads();
  if (t == 0) ws[WS_NBG + bb] = red[0] + red[1] + red[2] + red[3];

  // phase 2: build B-frags. slot (s, l): proto p = l&15, c-base = 32s + (l>>4)*4
  typedef __attribute__((ext_vector_type(8))) unsigned short v8u;
  v8u* Bhi = (v8u*)(ws + WS_BHI);
  v8u* Blo = (v8u*)(ws + WS_BLO);
  for (int idx = t; idx < NSTEP * 64; idx += 256) {
    int s = idx >> 6, l = idx & 63;
    int p = l & 15, q4 = (l >> 4) * 4;
    float rp = rnl[p];
    const float* src = protos + ((size_t)(bb * KP + p)) * CDIM + 32 * s + q4;
    float4 va = *(const float4*)(src);        // j = 0..3  (k = q4+0..3)
    float4 vb = *(const float4*)(src + 16);   // j = 4..7  (k = 16+q4+0..3)
    float vals[8] = { va.x * rp, va.y * rp, va.z * rp, va.w * rp,
                      vb.x * rp, vb.y * rp, vb.z * rp, vb.w * rp };
    v8u hv, lv;
    #pragma unroll
    for (int j = 0; j < 8; ++j) {
      unsigned short h, lo2;
      f2hl(vals[j], h, lo2);
      hv[j] = h; lv[j] = lo2;
    }
    int slot = (bb * NSTEP + s) * 64 + l;
    Bhi[slot] = hv;
    Blo[slot] = lv;
  }
}

// ---------------- kernel B: att + K build via MFMA ----------------
// grid (64, 8), block 256 = 4 waves; each wave owns a 16-row tile.
// A = feat rows (fp32 -> bf16 hi/lo on the fly), B = prepacked proto frags.
// acc = Ahi*Bhi + Alo*Bhi + Ahi*Blo  (~fp32 precision).
// Row norms via per-lane f^2 partials + xor16/xor32 shuffles.
// This replaces the VALU dot-product kernel whose 128-float per-lane proto
// array the allocator refused to keep resident (rounds 1-4: VGPR=84, spill
// to scratch, ~80-100 us). MFMA's B-frag gives the 16-row reuse in HW.
__global__ __launch_bounds__(256, 4) void attk_kernel(
    const float* __restrict__ feat, const int* __restrict__ masks,
    const float* __restrict__ ws, float* __restrict__ Kmat) {
  int bb = blockIdx.y;
  int w = threadIdx.x >> 6, lane = threadIdx.x & 63;
  int n0 = blockIdx.x * 64 + w * 16;
  int rowa = lane & 15;          // A-frag row / B-frag col(proto)
  int quad = lane >> 4;          // k-chunk selector

  const v8s* Bhi = (const v8s*)(ws + WS_BHI) + (size_t)bb * NSTEP * 64 + lane;
  const v8s* Blo = (const v8s*)(ws + WS_BLO) + (size_t)bb * NSTEP * 64 + lane;
  const float* frow = feat + ((size_t)(bb * NUM + n0 + rowa)) * CDIM + quad * 4;

  v4f acc = {0.f, 0.f, 0.f, 0.f};
  float ss = 0.f;

  #pragma unroll 2
  for (int s = 0; s < NSTEP; ++s) {
    float4 va = *(const float4*)(frow + 32 * s);        // k = quad*4 + 0..3
    float4 vb = *(const float4*)(frow + 32 * s + 16);   // k = 16 + quad*4 + 0..3
    v8s bh = Bhi[s * 64];
    v8s bl = Blo[s * 64];
    float vals[8] = { va.x, va.y, va.z, va.w, vb.x, vb.y, vb.z, vb.w };
    v8s ah, al;
    #pragma unroll
    for (int j = 0; j < 8; ++j) {
      unsigned short h, lo2;
      f2hl(vals[j], h, lo2);
      ah[j] = (short)h; al[j] = (short)lo2;
      ss += vals[j] * vals[j];
    }
    acc = __builtin_amdgcn_mfma_f32_16x16x32_bf16(ah, bh, acc, 0, 0, 0);
    acc = __builtin_amdgcn_mfma_f32_16x16x32_bf16(al, bh, acc, 0, 0, 0);
    acc = __builtin_amdgcn_mfma_f32_16x16x32_bf16(ah, bl, acc, 0, 0, 0);
  }

  // full row norm for row (lane&15): lanes l, l^16, l^32, l^48 hold disjoint quarters
  ss += __shfl_xor(ss, 16, 64);
  ss += __shfl_xor(ss, 32, 64);
  float rn = 1.0f / fmaxf(sqrtf(ss), FEPS);

  // C/D layout (m89-verified): col = lane&15 (proto), row = quad*4 + q
  float* Kb = Kmat + (size_t)bb * NUM * KSTR;
  #pragma unroll
  for (int q = 0; q < 4; ++q) {
    int r = quad * 4 + q;
    float rq = __shfl(rn, r, 64);           // lane r (<16) holds row r's norm
    float kv = __expf((acc[q] * rq - 1.0f) * 20.0f);   // exp(-(1-att)/0.05)
    Kb[(size_t)(n0 + r) * KSTR + rowa] = kv;
  }
  if (lane < 16) {
    int mv = masks[bb * NUM + n0 + lane];
    // exp(-2/0.05) = exp(-40), or exp(0)=1
    Kb[(size_t)(n0 + lane) * KSTR + 16] = (mv > 0) ? 4.248354255291589e-18f : 1.0f;
  }
}

// ---------------- kernel C: 100 Sinkhorn iterations + epilogue ----------------
// 8 blocks (one per batch) x 512 threads; thread owns rows t + 512*j;
// K rows live in registers (launch_bounds(512,2) -> no spill, round 1 fix).
__global__ __launch_bounds__(512, 2) void sinkhorn_kernel(
    const float* __restrict__ Kmat, const float* __restrict__ numbg,
    float* __restrict__ out) {
  int bb = blockIdx.x;
  int t = threadIdx.x;
  const float* Kb = Kmat + (size_t)bb * NUM * KSTR;

  float kreg[8][KC];
  #pragma unroll
  for (int j = 0; j < 8; ++j) {
    int n = t + 512 * j;
    const float* kr = Kb + (size_t)n * KSTR;
    #pragma unroll
    for (int q = 0; q < 4; ++q) {
      float4 v = *(const float4*)(kr + 4 * q);
      kreg[j][4*q+0] = v.x; kreg[j][4*q+1] = v.y; kreg[j][4*q+2] = v.z; kreg[j][4*q+3] = v.w;
    }
    kreg[j][16] = kr[16];
  }

  float nbg   = numbg[bb];
  float rowp  = (4096.0f - nbg) * (1.0f / (16.0f * 4096.0f));
  float row16 = nbg * (1.0f / 4096.0f);
  const float col = 1.0f / 4096.0f;

  __shared__ float vlds[KC];
  __shared__ float part[KC][520];
  __shared__ int   flags[2];
  if (t < KC) vlds[t] = 1.0f;
  if (t == 0) { flags[0] = 0; flags[1] = 0; }
  __syncthreads();

  float u[8];
  #pragma unroll 1
  for (int it = 0; it < NITER; ++it) {
    float vr[KC];
    #pragma unroll
    for (int p = 0; p < KC; ++p) vr[p] = vlds[p];
    float s[KC];
    #pragma unroll
    for (int p = 0; p < KC; ++p) s[p] = 0.f;
    #pragma unroll
    for (int j = 0; j < 8; ++j) {
      float dot = 0.f;
      #pragma unroll
      for (int p = 0; p < KC; ++p) dot += kreg[j][p] * vr[p];
      float uu = col * __builtin_amdgcn_rcpf(fmaxf(dot, FEPS));
      u[j] = uu;
      #pragma unroll
      for (int p = 0; p < KC; ++p) s[p] += kreg[j][p] * uu;
    }
    #pragma unroll
    for (int p = 0; p < KC; ++p) part[p][t] = s[p];
    if (t == 0) flags[it & 1] = 0;
    __syncthreads();
    if (t < 272) {
      int k = t >> 4, i = t & 15;
      float acc = 0.f;
      #pragma unroll
      for (int j = 0; j < 32; ++j) acc += part[k][i + 16 * j];
      acc += __shfl_xor(acc, 1, 64);
      acc += __shfl_xor(acc, 2, 64);
      acc += __shfl_xor(acc, 4, 64);
      acc += __shfl_xor(acc, 8, 64);
      if (i == 0) {
        float rw = (k < KP) ? rowp : row16;
        float vold = vlds[k];
        float vnew = rw * __builtin_amdgcn_rcpf(fmaxf(acc, FEPS));
        vlds[k] = vnew;
        if (fabsf(vnew - vold) > 1e-6f * fabsf(vnew)) flags[it & 1] = 1;
      }
    }
    __syncthreads();
    if (flags[it & 1] == 0) break;
  }

  float vr[KC];
  #pragma unroll
  for (int p = 0; p < KC; ++p) vr[p] = vlds[p];
  float* ob = out + (size_t)bb * NUM * KP;
  #pragma unroll
  for (int j = 0; j < 8; ++j) {
    int n = t + 512 * j;
    float uu = u[j] * 4096.0f;
    float* dst = ob + (size_t)n * KP;
    #pragma unroll
    for (int q = 0; q < 4; ++q) {
      float4 v;
      v.x = fmaxf(uu * kreg[j][4*q+0] * vr[4*q+0], 0.f);
      v.y = fmaxf(uu * kreg[j][4*q+1] * vr[4*q+1], 0.f);
      v.z = fmaxf(uu * kreg[j][4*q+2] * vr[4*q+2], 0.f);
      v.w = fmaxf(uu * kreg[j][4*q+3] * vr[4*q+3], 0.f);
      *(float4*)(dst + 4 * q) = v;
    }
  }
}

extern "C" void kernel_launch(void* const* d_in, const int* in_sizes, int n_in,
                              void* d_out, int out_size, void* d_ws, size_t ws_size,
                              hipStream_t stream) {
  const float* feat   = (const float*)d_in[0];
  const float* protos = (const float*)d_in[1];
  const int*   masks  = (const int*)d_in[2];
  float* out = (float*)d_out;
  float* ws  = (float*)d_ws;

  float* Kmat  = ws + WS_K;
  float* numbg = ws + WS_NBG;

  hipLaunchKernelGGL(prep_kernel, dim3(NBATCH), dim3(256), 0, stream,
                     protos, masks, ws);
  hipLaunchKernelGGL(attk_kernel, dim3(64, NBATCH), dim3(256), 0, stream,
                     feat, masks, ws, Kmat);
  hipLaunchKernelGGL(sinkhorn_kernel, dim3(NBATCH), dim3(512), 0, stream,
                     Kmat, numbg, out);
}